// Round 1
// 371.441 us; speedup vs baseline: 1.1110x; 1.1110x over previous
//
#include <hip/hip_runtime.h>
#include <cstdint>
#include <cstddef>

typedef unsigned short u16;
typedef __bf16 bf16x8 __attribute__((ext_vector_type(8)));
typedef float  f32x4  __attribute__((ext_vector_type(4)));
typedef u16    u16x8v __attribute__((ext_vector_type(8)));
typedef u16    u16x4  __attribute__((ext_vector_type(4)));

#define EPS 1e-6f
#define BM 128
#define BN 128
#define BK 64   // u16 elems per row = 128 B = 8 chunks of 16 B

// ---------- helpers ----------
__device__ __forceinline__ u16 f2bf(float f) {
  union { float f; unsigned int u; } v; v.f = f;
  unsigned int u = v.u + 0x7FFFu + ((v.u >> 16) & 1u);   // RNE
  return (u16)(u >> 16);
}
__device__ __forceinline__ float bf2f(u16 h) {
  union { unsigned int u; float f; } v; v.u = ((unsigned int)h) << 16;
  return v.f;
}
__device__ __forceinline__ void async16(const void* g, void* l) {
  __builtin_amdgcn_global_load_lds(
      (const __attribute__((address_space(1))) void*)g,
      (__attribute__((address_space(3))) void*)l, 16, 0, 0);
}

// ---------- fp32 -> bf16 conversion ----------
__global__ __launch_bounds__(256) void cvt_bf16_kernel(
    const float* __restrict__ in, u16* __restrict__ out, int n8) {
  int i = blockIdx.x * 256 + threadIdx.x;
  if (i >= n8) return;
  const float4* p = (const float4*)in;
  float4 a = p[2 * (size_t)i], b = p[2 * (size_t)i + 1];
  u16x8v o;
  o[0] = f2bf(a.x); o[1] = f2bf(a.y); o[2] = f2bf(a.z); o[3] = f2bf(a.w);
  o[4] = f2bf(b.x); o[5] = f2bf(b.y); o[6] = f2bf(b.z); o[7] = f2bf(b.w);
  *(u16x8v*)(out + 8 * (size_t)i) = o;
}

// all four 1024x1024 weights in one launch (512 blocks each, exact cover)
__global__ __launch_bounds__(256) void cvt_w_kernel(
    const float* __restrict__ w0, const float* __restrict__ w1,
    const float* __restrict__ w2, const float* __restrict__ w3,
    u16* __restrict__ o0, u16* __restrict__ o1,
    u16* __restrict__ o2, u16* __restrict__ o3) {
  const int gb = blockIdx.x;
  const float* in = (gb < 512) ? w0 : (gb < 1024) ? w1 : (gb < 1536) ? w2 : w3;
  u16* out = (gb < 512) ? o0 : (gb < 1024) ? o1 : (gb < 1536) ? o2 : o3;
  const int i = (gb & 511) * 256 + threadIdx.x;   // 512*256*8 = 1024*1024
  const float4* p = (const float4*)in;
  float4 a = p[2 * (size_t)i], b = p[2 * (size_t)i + 1];
  u16x8v o;
  o[0] = f2bf(a.x); o[1] = f2bf(a.y); o[2] = f2bf(a.z); o[3] = f2bf(a.w);
  o[4] = f2bf(b.x); o[5] = f2bf(b.y); o[6] = f2bf(b.z); o[7] = f2bf(b.w);
  *(u16x8v*)(out + 8 * (size_t)i) = o;
}

// ---------- NT GEMM: C[M,N] = A[M,K] * B[N,K]^T + bias, opt phi ----------
// BK=64 (128 B rows). LDS chunk swizzle: global chunk g of row r lives at
// slot g ^ (r&7). global_load_lds writes linearly (lane l -> row +(l>>3),
// slot l&7), so the SOURCE chunk is pre-swizzled: (l&7)^(l>>3). Fragment
// reads XOR the same involution -> rows spread over 8 bank groups,
// 2 lanes/group (free) instead of the old 8-way conflict.
template <int ACT, typename OutT>
__global__ __launch_bounds__(256) void gemm_nt(
    const u16* __restrict__ A, const u16* __restrict__ Bm,
    const float* __restrict__ bias, OutT* __restrict__ C,
    int M, int N, int K) {
  __shared__ u16 sA[BM * BK];
  __shared__ u16 sB[BN * BK];

  const int tid  = threadIdx.x;
  const int wave = tid >> 6;
  const int lane = tid & 63;
  const int bm = blockIdx.x * BM;
  const int bn = blockIdx.y * BN;
  const int wm = (wave & 1) * 64;
  const int wn = (wave >> 1) * 64;

  f32x4 acc[4][4] = {};

  // staging: wave w owns rows [w*32, w*32+32) of sA and sB; 4 calls each,
  // call s covers rows w*32+s*8..+8 (1 KiB linear dest per call)
  const int srow   = wave * 32 + (lane >> 3);
  const int schunk = (lane & 7) ^ (lane >> 3);        // inverse swizzle on source
  const u16* gA0 = A  + (size_t)(bm + srow) * K + schunk * 8;
  const u16* gB0 = Bm + (size_t)(bn + srow) * K + schunk * 8;
  u16* lA = &sA[(wave * 32) * BK];
  u16* lB = &sB[(wave * 32) * BK];
  const size_t row8 = (size_t)8 * K;

  for (int k0 = 0; k0 < K; k0 += BK) {
    __syncthreads();
#pragma unroll
    for (int s = 0; s < 4; s++) {
      async16(gA0 + k0 + s * row8, lA + s * (8 * BK));
      async16(gB0 + k0 + s * row8, lB + s * (8 * BK));
    }
    __syncthreads();

#pragma unroll
    for (int kk = 0; kk < 2; kk++) {
      const int csw = ((kk * 4 + (lane >> 4)) ^ (lane & 7)) * 8;  // swizzled chunk
      bf16x8 af[4], bfv[4];
#pragma unroll
      for (int i = 0; i < 4; i++) {
        af[i]  = *(const bf16x8*)&sA[(wm + i * 16 + (lane & 15)) * BK + csw];
        bfv[i] = *(const bf16x8*)&sB[(wn + i * 16 + (lane & 15)) * BK + csw];
      }
#pragma unroll
      for (int mi = 0; mi < 4; mi++)
#pragma unroll
        for (int ni = 0; ni < 4; ni++)
          acc[mi][ni] = __builtin_amdgcn_mfma_f32_16x16x32_bf16(
              af[mi], bfv[ni], acc[mi][ni], 0, 0, 0);
    }
  }

  const int r0 = (lane >> 4) * 4;
  const int cc = lane & 15;
#pragma unroll
  for (int ni = 0; ni < 4; ni++) {
    const int col = bn + wn + ni * 16 + cc;
    const float bv = bias[col];
#pragma unroll
    for (int mi = 0; mi < 4; mi++) {
#pragma unroll
      for (int j = 0; j < 4; j++) {
        const int row = bm + wm + mi * 16 + r0 + j;
        float val = acc[mi][ni][j] + bv;
        if (ACT) val = (val > 0.f) ? (val + 1.f) : __expf(val);  // phi = elu+1
        if constexpr (sizeof(OutT) == 2)
          C[(size_t)row * N + col] = (OutT)f2bf(val);
        else
          C[(size_t)row * N + col] = (OutT)val;
      }
    }
  }
}

// ---------- kv via MFMA: kv[bh][d][m] = sum_t K[t,d]*V[t,m]; ksum via ones-B ----------
// grid (8 chunks, 64 bh), block 256 = 4 waves. Each block: 512 timesteps, 8 stages of 64 t.
// LDS layout: s{K,V}T[row][col] with rotation col = (t + 8*(row>>3)) & 63 so that the
// transposed b64 writes spread across banks (~2-way, free) while frag reads stay b128.
__global__ __launch_bounds__(256) void kv_mfma_kernel(
    const u16* __restrict__ Kb, const u16* __restrict__ Vb,
    float* __restrict__ kv, float* __restrict__ ksum) {
  const int bh = blockIdx.y;
  const int chunk = blockIdx.x;
  const int b = bh >> 4, h = bh & 15;
  const int tid = threadIdx.x, wave = tid >> 6, lane = tid & 63;

  __shared__ u16 sKT[64 * 64];   // [d][t'] rotated
  __shared__ u16 sVT[64 * 64];   // [m][t'] rotated

  f32x4 acc[4] = {};    // 4 d-tiles x (my m-tile = wave)
  f32x4 accs[4] = {};   // wave 0: ksum via ones-B (every column = ksum)

  union { u16x8v u; bf16x8 b; } uo;
#pragma unroll
  for (int e = 0; e < 8; e++) uo.u[e] = 0x3F80;   // bf16 1.0
  const bf16x8 ones = uo.b;

  // staging assignment: threads 0..127 -> K, 128..255 -> V
  const int half = tid >> 7;          // 0=K, 1=V
  const int j    = tid & 127;
  const int tg   = j >> 3;            // 0..15 (4 t-rows each)
  const int dg   = j & 7;             // 0..7  (8 d-cols each)
  const u16* src = half ? Vb : Kb;
  u16* dst = half ? sVT : sKT;
  const int colb = (4 * tg + 8 * dg) & 63;   // rotated column base (mult of 4)

  const size_t rowBase = (size_t)b * 4096 + (size_t)chunk * 512;
  const size_t gbase = (rowBase + 4 * tg) * 1024 + (size_t)h * 64 + dg * 8;

  u16x8v pre[2][4];
#pragma unroll
  for (int s = 0; s < 4; s++)
    pre[0][s] = *(const u16x8v*)(src + gbase + (size_t)s * 1024);

#pragma unroll
  for (int st = 0; st < 8; st++) {
    const int cb = st & 1;
    __syncthreads();                 // prev stage's frag reads done
    // transposed write: 8 x ds_write_b64
#pragma unroll
    for (int e = 0; e < 8; e++) {
      u16x4 w;
      w[0] = pre[cb][0][e]; w[1] = pre[cb][1][e];
      w[2] = pre[cb][2][e]; w[3] = pre[cb][3][e];
      *(u16x4*)&dst[(dg * 8 + e) * 64 + colb] = w;
    }
    // prefetch next stage (overlaps MFMA below)
    if (st + 1 < 8) {
      const size_t nb = gbase + (size_t)(st + 1) * 64 * 1024;
#pragma unroll
      for (int s = 0; s < 4; s++)
        pre[cb ^ 1][s] = *(const u16x8v*)(src + nb + (size_t)s * 1024);
    }
    __syncthreads();                 // LDS ready

#pragma unroll
    for (int kst = 0; kst < 2; kst++) {
      const int q8 = kst * 32 + (lane >> 4) * 8;
      bf16x8 bfrag;
      {
        const int rr = wave * 16 + (lane & 15);
        const int c = (q8 + 8 * (rr >> 3)) & 63;
        bfrag = *(const bf16x8*)&sVT[rr * 64 + c];
      }
#pragma unroll
      for (int i = 0; i < 4; i++) {
        const int rr = i * 16 + (lane & 15);
        const int c = (q8 + 8 * (rr >> 3)) & 63;
        const bf16x8 afrag = *(const bf16x8*)&sKT[rr * 64 + c];
        acc[i] = __builtin_amdgcn_mfma_f32_16x16x32_bf16(afrag, bfrag, acc[i], 0, 0, 0);
        if (wave == 0)
          accs[i] = __builtin_amdgcn_mfma_f32_16x16x32_bf16(afrag, ones, accs[i], 0, 0, 0);
      }
    }
  }

  // C/D layout: col=lane&15, row=(lane>>4)*4+j
  const int r0 = (lane >> 4) * 4, cc = lane & 15;
  float* kvp = kv + (size_t)bh * 4096;
#pragma unroll
  for (int i = 0; i < 4; i++)
#pragma unroll
    for (int jj = 0; jj < 4; jj++)
      atomicAdd(&kvp[(size_t)(i * 16 + r0 + jj) * 64 + wave * 16 + cc], acc[i][jj]);
  if (wave == 0 && cc == 0) {
#pragma unroll
    for (int i = 0; i < 4; i++)
#pragma unroll
      for (int jj = 0; jj < 4; jj++)
        atomicAdd(&ksum[(size_t)bh * 64 + i * 16 + r0 + jj], accs[i][jj]);
  }
}

// ---------- attn[t, h*64+m] = (Q[t,:] @ kv) * z[t] ----------
#define QST 80
__global__ __launch_bounds__(256) void attn_apply_kernel(
    const u16* __restrict__ Qb, const float* __restrict__ kv,
    const float* __restrict__ ksum, u16* __restrict__ attn) {
  const int bh = blockIdx.y;
  const int tt = blockIdx.x;
  const int b = bh >> 4, h = bh & 15;
  const int tid = threadIdx.x, wave = tid >> 6, lane = tid & 63;

  __shared__ u16 skvT[64 * QST];   // [m][d] = kv[d][m] as bf16
  __shared__ u16 sq[64 * QST];     // [t][d]
  __shared__ float sz[64];
  __shared__ float sks[64];

  if (tid < 64) sks[tid] = ksum[(size_t)bh * 64 + tid] + EPS;

  const float* kvp = kv + (size_t)bh * 4096;
  for (int i = tid; i < 4096; i += 256) {
    const int dd = i >> 6, mm = i & 63;
    skvT[mm * QST + dd] = f2bf(kvp[i]);
  }
  const size_t qbase = ((size_t)b * 4096 + (size_t)tt * 64) * 1024 + h * 64;
  for (int i = tid; i < 4096; i += 256) {
    const int r = i >> 6, dd = i & 63;
    sq[r * QST + dd] = Qb[qbase + (size_t)r * 1024 + dd];
  }
  __syncthreads();

  if (tid < 64) {
    float za = 0.f;
#pragma unroll
    for (int j = 0; j < 64; j++) {
      const int dd = (j + tid) & 63;
      za += bf2f(sq[tid * QST + dd]) * sks[dd];
    }
    sz[tid] = 1.f / (za + EPS);
  }
  __syncthreads();

  f32x4 acc[4] = {};
#pragma unroll
  for (int ks2 = 0; ks2 < 2; ks2++) {
    const bf16x8 a = *(const bf16x8*)&sq[(wave * 16 + (lane & 15)) * QST + ks2 * 32 + (lane >> 4) * 8];
#pragma unroll
    for (int ni = 0; ni < 4; ni++) {
      const bf16x8 bv = *(const bf16x8*)&skvT[(ni * 16 + (lane & 15)) * QST + ks2 * 32 + (lane >> 4) * 8];
      acc[ni] = __builtin_amdgcn_mfma_f32_16x16x32_bf16(a, bv, acc[ni], 0, 0, 0);
    }
  }

  const int r0 = (lane >> 4) * 4, cc = lane & 15;
#pragma unroll
  for (int ni = 0; ni < 4; ni++) {
#pragma unroll
    for (int j = 0; j < 4; j++) {
      const int r = wave * 16 + r0 + j;
      const int c = ni * 16 + cc;
      const float val = acc[ni][j] * sz[r];
      attn[qbase + (size_t)r * 1024 + c] = f2bf(val);
    }
  }
}

// ---------- launch ----------
extern "C" void kernel_launch(void* const* d_in, const int* in_sizes, int n_in,
                              void* d_out, int out_size, void* d_ws, size_t ws_size,
                              hipStream_t stream) {
  (void)in_sizes; (void)n_in; (void)out_size; (void)ws_size;
  const float* x  = (const float*)d_in[0];
  const float* Wq = (const float*)d_in[1];
  const float* bq = (const float*)d_in[2];
  const float* Wk = (const float*)d_in[3];
  const float* bk = (const float*)d_in[4];
  const float* Wv = (const float*)d_in[5];
  const float* bv = (const float*)d_in[6];
  const float* Wo = (const float*)d_in[7];
  const float* bo = (const float*)d_in[8];

  // B=4, T=4096, D=1024, H=16, DK=64; M = B*T = 16384
  char* ws = (char*)d_ws;
  u16* xb   = (u16*)ws;  ws += 33554432;               // [16384,1024] bf16
  u16* wqb  = (u16*)ws;  ws += 2097152;
  u16* wkb  = (u16*)ws;  ws += 2097152;
  u16* wvb  = (u16*)ws;  ws += 2097152;
  u16* wob  = (u16*)ws;  ws += 2097152;
  u16* Vb   = (u16*)ws;  ws += 33554432;
  u16* attn = (u16*)ws;  ws += 33554432;
  float* kvb  = (float*)ws; ws += 1048576;             // [64][64][64] fp32
  float* ksum = (float*)ws; ws += 16384;               // [64][64] fp32

  u16* Qb = (u16*)d_out;
  u16* Kb = Qb + 16777216;

  hipMemsetAsync(kvb, 0, 1048576 + 16384, stream);

  cvt_bf16_kernel<<<8192, 256, 0, stream>>>(x,  xb,  2097152);
  cvt_w_kernel<<<2048, 256, 0, stream>>>(Wq, Wk, Wv, Wo, wqb, wkb, wvb, wob);

  dim3 gg(128, 8), blk(256);
  gemm_nt<1, u16><<<gg, blk, 0, stream>>>(xb, wqb, bq, Qb, 16384, 1024, 1024);
  gemm_nt<1, u16><<<gg, blk, 0, stream>>>(xb, wkb, bk, Kb, 16384, 1024, 1024);
  gemm_nt<0, u16><<<gg, blk, 0, stream>>>(xb, wvb, bv, Vb, 16384, 1024, 1024);

  kv_mfma_kernel<<<dim3(8, 64), blk, 0, stream>>>(Kb, Vb, kvb, ksum);
  attn_apply_kernel<<<dim3(64, 64), blk, 0, stream>>>(Qb, kvb, ksum, attn);

  gemm_nt<0, float><<<gg, blk, 0, stream>>>(attn, wob, bo, (float*)d_out,
                                            16384, 1024, 1024);
}

// Round 2
// 367.415 us; speedup vs baseline: 1.1232x; 1.0110x over previous
//
#include <hip/hip_runtime.h>
#include <cstdint>
#include <cstddef>

typedef unsigned short u16;
typedef __bf16 bf16x8 __attribute__((ext_vector_type(8)));
typedef float  f32x4  __attribute__((ext_vector_type(4)));
typedef u16    u16x8v __attribute__((ext_vector_type(8)));
typedef u16    u16x4  __attribute__((ext_vector_type(4)));

#define EPS 1e-6f

// ---------- helpers ----------
__device__ __forceinline__ u16 f2bf(float f) {
  union { float f; unsigned int u; } v; v.f = f;
  unsigned int u = v.u + 0x7FFFu + ((v.u >> 16) & 1u);   // RNE
  return (u16)(u >> 16);
}
__device__ __forceinline__ float bf2f(u16 h) {
  union { unsigned int u; float f; } v; v.u = ((unsigned int)h) << 16;
  return v.f;
}
__device__ __forceinline__ void async16(const void* g, void* l) {
  __builtin_amdgcn_global_load_lds(
      (const __attribute__((address_space(1))) void*)g,
      (__attribute__((address_space(3))) void*)l, 16, 0, 0);
}

// ---------- fp32 -> bf16 conversion ----------
__global__ __launch_bounds__(256) void cvt_bf16_kernel(
    const float* __restrict__ in, u16* __restrict__ out, int n8) {
  int i = blockIdx.x * 256 + threadIdx.x;
  if (i >= n8) return;
  const float4* p = (const float4*)in;
  float4 a = p[2 * (size_t)i], b = p[2 * (size_t)i + 1];
  u16x8v o;
  o[0] = f2bf(a.x); o[1] = f2bf(a.y); o[2] = f2bf(a.z); o[3] = f2bf(a.w);
  o[4] = f2bf(b.x); o[5] = f2bf(b.y); o[6] = f2bf(b.z); o[7] = f2bf(b.w);
  *(u16x8v*)(out + 8 * (size_t)i) = o;
}

// all four 1024x1024 weights in one launch (512 blocks each, exact cover)
__global__ __launch_bounds__(256) void cvt_w_kernel(
    const float* __restrict__ w0, const float* __restrict__ w1,
    const float* __restrict__ w2, const float* __restrict__ w3,
    u16* __restrict__ o0, u16* __restrict__ o1,
    u16* __restrict__ o2, u16* __restrict__ o3) {
  const int gb = blockIdx.x;
  const float* in = (gb < 512) ? w0 : (gb < 1024) ? w1 : (gb < 1536) ? w2 : w3;
  u16* out = (gb < 512) ? o0 : (gb < 1024) ? o1 : (gb < 1536) ? o2 : o3;
  const int i = (gb & 511) * 256 + threadIdx.x;   // 512*256*8 = 1024*1024
  const float4* p = (const float4*)in;
  float4 a = p[2 * (size_t)i], b = p[2 * (size_t)i + 1];
  u16x8v o;
  o[0] = f2bf(a.x); o[1] = f2bf(a.y); o[2] = f2bf(a.z); o[3] = f2bf(a.w);
  o[4] = f2bf(b.x); o[5] = f2bf(b.y); o[6] = f2bf(b.z); o[7] = f2bf(b.w);
  *(u16x8v*)(out + 8 * (size_t)i) = o;
}

// ---------- 256x256 2-phase NT GEMM (T3-minimum, verified recipe) ----------
// 512 threads = 8 waves (2M x 4N), per-wave output 128x64 (8x4 frags of 16x16).
// BK=64 (128 B rows = 8 chunks of 16 B). Double-buffered LDS: 2 x (A 32K + B 32K)
// = 128 KiB, 1 block/CU. Chunk swizzle (verified 0-conflict in R1): data chunk c
// of row r lives at slot c^(r&7); global_load_lds writes linearly, so the SOURCE
// chunk is pre-swizzled per-lane and the READ applies the same XOR (rule #21).
// K-loop: STAGE(next buf) BEFORE ds_read+MFMA(cur), one __syncthreads per step
// (its vmcnt drain lands after the MFMA span -> load latency hidden).
// MODE=1: fused QKV (N=3072, bn>>2 selects matrix; phi for Q,K). MODE=0: fp32 out.
template <int MODE>
__global__ __launch_bounds__(512) void gemm2p(
    const u16* __restrict__ A, const u16* __restrict__ Bw,
    const float* __restrict__ bias0, const float* __restrict__ bias1,
    const float* __restrict__ bias2,
    u16* __restrict__ O0, u16* __restrict__ O1, u16* __restrict__ O2,
    float* __restrict__ Of, int K) {
  __shared__ u16 sA[2][256 * 64];
  __shared__ u16 sB[2][256 * 64];

  const int tid  = threadIdx.x;
  const int wave = tid >> 6;
  const int lane = tid & 63;
  const int bm = blockIdx.x * 256;
  const int bn = blockIdx.y * 256;
  const int wm = (wave >> 2) * 128;     // 2 M-halves
  const int wn = (wave & 3) * 64;      // 4 N-quarters

  f32x4 acc[8][4] = {};

  // staging: thread tid covers (row tid>>3, src-chunk swizzled), 4 calls/matrix,
  // call s covers rows s*64..s*64+63; per-wave dest base is wave-uniform.
  const int srow = tid >> 3;
  const int sch8 = ((tid & 7) ^ ((tid >> 3) & 7)) * 8;
  const u16* gA0 = A  + (size_t)(bm + srow) * K + sch8;
  const u16* gB0 = Bw + (size_t)(bn + srow) * K + sch8;
  const int dwb = wave * 8 * 64;       // wave-uniform dest offset (elems)

#define STAGE2P(buf, k0)                                           \
  {                                                                \
    _Pragma("unroll")                                              \
    for (int s = 0; s < 4; s++) {                                  \
      async16(gA0 + (size_t)(k0) + (size_t)s * 64 * K,             \
              &sA[buf][s * 64 * 64 + dwb]);                        \
      async16(gB0 + (size_t)(k0) + (size_t)s * 64 * K,             \
              &sB[buf][s * 64 * 64 + dwb]);                        \
    }                                                              \
  }

  const int l15 = lane & 15, l4 = lane >> 4, l7 = lane & 7;

  // prologue: stage tile 0, drain, enter loop
  STAGE2P(0, 0);
  __syncthreads();

  int cur = 0;
  const int NT = K >> 6;               // 16 K-tiles
  for (int t = 0; t < NT; ++t) {
    if (t + 1 < NT) STAGE2P(cur ^ 1, (t + 1) * 64);   // prefetch next tile
#pragma unroll
    for (int kk = 0; kk < 2; kk++) {
      const int slot = ((kk * 4 + l4) ^ l7) * 8;
      bf16x8 af[8], bfv[4];
#pragma unroll
      for (int i = 0; i < 8; i++)
        af[i] = *(const bf16x8*)&sA[cur][(wm + i * 16 + l15) * 64 + slot];
#pragma unroll
      for (int n = 0; n < 4; n++)
        bfv[n] = *(const bf16x8*)&sB[cur][(wn + n * 16 + l15) * 64 + slot];
#pragma unroll
      for (int mi = 0; mi < 8; mi++)
#pragma unroll
        for (int ni = 0; ni < 4; ni++)
          acc[mi][ni] = __builtin_amdgcn_mfma_f32_16x16x32_bf16(
              af[mi], bfv[ni], acc[mi][ni], 0, 0, 0);
    }
    __syncthreads();                   // drains vmcnt: next tile landed
    cur ^= 1;
  }
#undef STAGE2P

  // epilogue. C/D layout: col=lane&15, row=(lane>>4)*4+j (verified).
  const int r0 = (lane >> 4) * 4, cc = lane & 15;
  if constexpr (MODE == 1) {
    const int mat = blockIdx.y >> 2;                    // 0=Q 1=K 2=V
    u16* outp = (mat == 0) ? O0 : (mat == 1) ? O1 : O2;
    const float* bias = (mat == 0) ? bias0 : (mat == 1) ? bias1 : bias2;
    const int act = (mat < 2);
    const int colb = (blockIdx.y & 3) * 256;
#pragma unroll
    for (int ni = 0; ni < 4; ni++) {
      const int col = colb + wn + ni * 16 + cc;
      const float bv = bias[col];
#pragma unroll
      for (int mi = 0; mi < 8; mi++) {
#pragma unroll
        for (int j = 0; j < 4; j++) {
          const int row = bm + wm + mi * 16 + r0 + j;
          float val = acc[mi][ni][j] + bv;
          if (act) val = (val > 0.f) ? (val + 1.f) : __expf(val);  // phi
          outp[(size_t)row * 1024 + col] = f2bf(val);
        }
      }
    }
  } else {
#pragma unroll
    for (int ni = 0; ni < 4; ni++) {
      const int col = bn + wn + ni * 16 + cc;
      const float bv = bias0[col];
#pragma unroll
      for (int mi = 0; mi < 8; mi++) {
#pragma unroll
        for (int j = 0; j < 4; j++) {
          const int row = bm + wm + mi * 16 + r0 + j;
          Of[(size_t)row * 1024 + col] = acc[mi][ni][j] + bv;
        }
      }
    }
  }
}

// ---------- kv via MFMA: kv[bh][d][m] = sum_t K[t,d]*V[t,m]; ksum via ones-B ----------
__global__ __launch_bounds__(256) void kv_mfma_kernel(
    const u16* __restrict__ Kb, const u16* __restrict__ Vb,
    float* __restrict__ kv, float* __restrict__ ksum) {
  const int bh = blockIdx.y;
  const int chunk = blockIdx.x;
  const int b = bh >> 4, h = bh & 15;
  const int tid = threadIdx.x, wave = tid >> 6, lane = tid & 63;

  __shared__ u16 sKT[64 * 64];   // [d][t'] rotated
  __shared__ u16 sVT[64 * 64];   // [m][t'] rotated

  f32x4 acc[4] = {};
  f32x4 accs[4] = {};

  union { u16x8v u; bf16x8 b; } uo;
#pragma unroll
  for (int e = 0; e < 8; e++) uo.u[e] = 0x3F80;   // bf16 1.0
  const bf16x8 ones = uo.b;

  const int half = tid >> 7;          // 0=K, 1=V
  const int j    = tid & 127;
  const int tg   = j >> 3;            // 0..15 (4 t-rows each)
  const int dg   = j & 7;             // 0..7  (8 d-cols each)
  const u16* src = half ? Vb : Kb;
  u16* dst = half ? sVT : sKT;
  const int colb = (4 * tg + 8 * dg) & 63;

  const size_t rowBase = (size_t)b * 4096 + (size_t)chunk * 512;
  const size_t gbase = (rowBase + 4 * tg) * 1024 + (size_t)h * 64 + dg * 8;

  u16x8v pre[2][4];
#pragma unroll
  for (int s = 0; s < 4; s++)
    pre[0][s] = *(const u16x8v*)(src + gbase + (size_t)s * 1024);

#pragma unroll
  for (int st = 0; st < 8; st++) {
    const int cb = st & 1;
    __syncthreads();
#pragma unroll
    for (int e = 0; e < 8; e++) {
      u16x4 w;
      w[0] = pre[cb][0][e]; w[1] = pre[cb][1][e];
      w[2] = pre[cb][2][e]; w[3] = pre[cb][3][e];
      *(u16x4*)&dst[(dg * 8 + e) * 64 + colb] = w;
    }
    if (st + 1 < 8) {
      const size_t nb = gbase + (size_t)(st + 1) * 64 * 1024;
#pragma unroll
      for (int s = 0; s < 4; s++)
        pre[cb ^ 1][s] = *(const u16x8v*)(src + nb + (size_t)s * 1024);
    }
    __syncthreads();

#pragma unroll
    for (int kst = 0; kst < 2; kst++) {
      const int q8 = kst * 32 + (lane >> 4) * 8;
      bf16x8 bfrag;
      {
        const int rr = wave * 16 + (lane & 15);
        const int c = (q8 + 8 * (rr >> 3)) & 63;
        bfrag = *(const bf16x8*)&sVT[rr * 64 + c];
      }
#pragma unroll
      for (int i = 0; i < 4; i++) {
        const int rr = i * 16 + (lane & 15);
        const int c = (q8 + 8 * (rr >> 3)) & 63;
        const bf16x8 afrag = *(const bf16x8*)&sKT[rr * 64 + c];
        acc[i] = __builtin_amdgcn_mfma_f32_16x16x32_bf16(afrag, bfrag, acc[i], 0, 0, 0);
        if (wave == 0)
          accs[i] = __builtin_amdgcn_mfma_f32_16x16x32_bf16(afrag, ones, accs[i], 0, 0, 0);
      }
    }
  }

  const int r0 = (lane >> 4) * 4, cc = lane & 15;
  float* kvp = kv + (size_t)bh * 4096;
#pragma unroll
  for (int i = 0; i < 4; i++)
#pragma unroll
    for (int jj = 0; jj < 4; jj++)
      atomicAdd(&kvp[(size_t)(i * 16 + r0 + jj) * 64 + wave * 16 + cc], acc[i][jj]);
  if (wave == 0 && cc == 0) {
#pragma unroll
    for (int i = 0; i < 4; i++)
#pragma unroll
      for (int jj = 0; jj < 4; jj++)
        atomicAdd(&ksum[(size_t)bh * 64 + i * 16 + r0 + jj], accs[i][jj]);
  }
}

// ---------- attn[t, h*64+m] = (Q[t,:] @ kv) * z[t] ----------
#define QST 80
__global__ __launch_bounds__(256) void attn_apply_kernel(
    const u16* __restrict__ Qb, const float* __restrict__ kv,
    const float* __restrict__ ksum, u16* __restrict__ attn) {
  const int bh = blockIdx.y;
  const int tt = blockIdx.x;
  const int b = bh >> 4, h = bh & 15;
  const int tid = threadIdx.x, wave = tid >> 6, lane = tid & 63;

  __shared__ u16 skvT[64 * QST];
  __shared__ u16 sq[64 * QST];
  __shared__ float sz[64];
  __shared__ float sks[64];

  if (tid < 64) sks[tid] = ksum[(size_t)bh * 64 + tid] + EPS;

  const float* kvp = kv + (size_t)bh * 4096;
  for (int i = tid; i < 4096; i += 256) {
    const int dd = i >> 6, mm = i & 63;
    skvT[mm * QST + dd] = f2bf(kvp[i]);
  }
  const size_t qbase = ((size_t)b * 4096 + (size_t)tt * 64) * 1024 + h * 64;
  for (int i = tid; i < 4096; i += 256) {
    const int r = i >> 6, dd = i & 63;
    sq[r * QST + dd] = Qb[qbase + (size_t)r * 1024 + dd];
  }
  __syncthreads();

  if (tid < 64) {
    float za = 0.f;
#pragma unroll
    for (int j = 0; j < 64; j++) {
      const int dd = (j + tid) & 63;
      za += bf2f(sq[tid * QST + dd]) * sks[dd];
    }
    sz[tid] = 1.f / (za + EPS);
  }
  __syncthreads();

  f32x4 acc[4] = {};
#pragma unroll
  for (int ks2 = 0; ks2 < 2; ks2++) {
    const bf16x8 a = *(const bf16x8*)&sq[(wave * 16 + (lane & 15)) * QST + ks2 * 32 + (lane >> 4) * 8];
#pragma unroll
    for (int ni = 0; ni < 4; ni++) {
      const bf16x8 bv = *(const bf16x8*)&skvT[(ni * 16 + (lane & 15)) * QST + ks2 * 32 + (lane >> 4) * 8];
      acc[ni] = __builtin_amdgcn_mfma_f32_16x16x32_bf16(a, bv, acc[ni], 0, 0, 0);
    }
  }

  const int r0 = (lane >> 4) * 4, cc = lane & 15;
#pragma unroll
  for (int ni = 0; ni < 4; ni++) {
#pragma unroll
    for (int j = 0; j < 4; j++) {
      const int r = wave * 16 + r0 + j;
      const int c = ni * 16 + cc;
      const float val = acc[ni][j] * sz[r];
      attn[qbase + (size_t)r * 1024 + c] = f2bf(val);
    }
  }
}

// ---------- launch ----------
extern "C" void kernel_launch(void* const* d_in, const int* in_sizes, int n_in,
                              void* d_out, int out_size, void* d_ws, size_t ws_size,
                              hipStream_t stream) {
  (void)in_sizes; (void)n_in; (void)out_size; (void)ws_size;
  const float* x  = (const float*)d_in[0];
  const float* Wq = (const float*)d_in[1];
  const float* bq = (const float*)d_in[2];
  const float* Wk = (const float*)d_in[3];
  const float* bk = (const float*)d_in[4];
  const float* Wv = (const float*)d_in[5];
  const float* bv = (const float*)d_in[6];
  const float* Wo = (const float*)d_in[7];
  const float* bo = (const float*)d_in[8];

  // B=4, T=4096, D=1024, H=16, DK=64; M = B*T = 16384
  char* ws = (char*)d_ws;
  u16* xb    = (u16*)ws;  ws += 33554432;              // [16384,1024] bf16
  u16* wqkvb = (u16*)ws;  ws += 6291456;               // [3072,1024] bf16 (Q|K|V)
  u16* wob   = (u16*)ws;  ws += 2097152;
  u16* Vb    = (u16*)ws;  ws += 33554432;
  u16* attn  = (u16*)ws;  ws += 33554432;
  float* kvb  = (float*)ws; ws += 1048576;             // [64][64][64] fp32
  float* ksum = (float*)ws; ws += 16384;               // [64][64] fp32

  u16* Qb = (u16*)d_out;
  u16* Kb = Qb + 16777216;

  hipMemsetAsync(kvb, 0, 1048576 + 16384, stream);

  cvt_bf16_kernel<<<8192, 256, 0, stream>>>(x, xb, 2097152);
  cvt_w_kernel<<<2048, 256, 0, stream>>>(Wq, Wk, Wv, Wo,
                                         wqkvb, wqkvb + 1048576, wqkvb + 2097152, wob);

  // fused QKV GEMM: [16384,1024] x [3072,1024]^T, N=3072
  gemm2p<1><<<dim3(64, 12), 512, 0, stream>>>(
      xb, wqkvb, bq, bk, bv, Qb, Kb, Vb, nullptr, 1024);

  kv_mfma_kernel<<<dim3(8, 64), dim3(256), 0, stream>>>(Kb, Vb, kvb, ksum);
  attn_apply_kernel<<<dim3(64, 64), dim3(256), 0, stream>>>(Qb, kvb, ksum, attn);

  // output GEMM: [16384,1024] x [1024,1024]^T -> fp32
  gemm2p<0><<<dim3(64, 4), 512, 0, stream>>>(
      attn, wob, bo, nullptr, nullptr, nullptr, nullptr, nullptr,
      (float*)d_out, 1024);
}

// Round 3
// 337.998 us; speedup vs baseline: 1.2209x; 1.0870x over previous
//
#include <hip/hip_runtime.h>
#include <cstdint>
#include <cstddef>

typedef unsigned short u16;
typedef __bf16 bf16x8 __attribute__((ext_vector_type(8)));
typedef float  f32x4  __attribute__((ext_vector_type(4)));
typedef u16    u16x8v __attribute__((ext_vector_type(8)));
typedef u16    u16x4  __attribute__((ext_vector_type(4)));

#define EPS 1e-6f

// ---------- helpers ----------
__device__ __forceinline__ u16 f2bf(float f) {
  union { float f; unsigned int u; } v; v.f = f;
  unsigned int u = v.u + 0x7FFFu + ((v.u >> 16) & 1u);   // RNE
  return (u16)(u >> 16);
}
__device__ __forceinline__ float bf2f(u16 h) {
  union { unsigned int u; float f; } v; v.u = ((unsigned int)h) << 16;
  return v.f;
}
__device__ __forceinline__ void async16(const void* g, void* l) {
  __builtin_amdgcn_global_load_lds(
      (const __attribute__((address_space(1))) void*)g,
      (__attribute__((address_space(3))) void*)l, 16, 0, 0);
}

// ---------- fp32 -> bf16 conversion ----------
__global__ __launch_bounds__(256) void cvt_bf16_kernel(
    const float* __restrict__ in, u16* __restrict__ out, int n8) {
  int i = blockIdx.x * 256 + threadIdx.x;
  if (i >= n8) return;
  const float4* p = (const float4*)in;
  float4 a = p[2 * (size_t)i], b = p[2 * (size_t)i + 1];
  u16x8v o;
  o[0] = f2bf(a.x); o[1] = f2bf(a.y); o[2] = f2bf(a.z); o[3] = f2bf(a.w);
  o[4] = f2bf(b.x); o[5] = f2bf(b.y); o[6] = f2bf(b.z); o[7] = f2bf(b.w);
  *(u16x8v*)(out + 8 * (size_t)i) = o;
}

__global__ __launch_bounds__(256) void cvt_w_kernel(
    const float* __restrict__ w0, const float* __restrict__ w1,
    const float* __restrict__ w2, const float* __restrict__ w3,
    u16* __restrict__ o0, u16* __restrict__ o1,
    u16* __restrict__ o2, u16* __restrict__ o3) {
  const int gb = blockIdx.x;
  const float* in = (gb < 512) ? w0 : (gb < 1024) ? w1 : (gb < 1536) ? w2 : w3;
  u16* out = (gb < 512) ? o0 : (gb < 1024) ? o1 : (gb < 1536) ? o2 : o3;
  const int i = (gb & 511) * 256 + threadIdx.x;
  const float4* p = (const float4*)in;
  float4 a = p[2 * (size_t)i], b = p[2 * (size_t)i + 1];
  u16x8v o;
  o[0] = f2bf(a.x); o[1] = f2bf(a.y); o[2] = f2bf(a.z); o[3] = f2bf(a.w);
  o[4] = f2bf(b.x); o[5] = f2bf(b.y); o[6] = f2bf(b.z); o[7] = f2bf(b.w);
  *(u16x8v*)(out + 8 * (size_t)i) = o;
}

// ---------- 256x256 8-phase NT GEMM with counted vmcnt (T2+T3+T4+T5) ----------
// 512 thr = 8 waves (2M x 4N), per-wave C = 128x64. BK=64. LDS = 2 bufs x (A+B)
// = 128 KiB. Tiles half-grouped: A-half qm = rows with bit6==qm stored at LDS
// rows [qm*128, qm*128+128); B-half qn = rows with bit5==qn likewise. Per-wave
// quadrant (qm,qn) per phase reads EXACTLY one A-half + one B-half, so each
// half dies 2 phases before its slot is re-staged (WAR safe via barriers).
// Stage order per iter (E=2i buf0, O=2i+1 buf1):
//   p0:+O.A1  p1:+O.B1  p2:+E2.A0  p3:+E2.B0  p4:+E2.A1  p5:+E2.B1
//   p6:+O2.A0 p7:+O2.B0      (O2.A1/B1 land at next iter's p0/p1)
// Waits: vmcnt(4) before p3's and p7's mid-barrier (exact: 4 loads younger than
// the youngest feeder of the next 4 phases); wait+barrier => cross-wave visible.
// Chunk swizzle (0-conflict, R1-verified): slot = (chunk ^ (row&7)); source
// pre-swizzled, read XORed — row&7 == lane&7 in both layouts.
template <int MODE>
__global__ __launch_bounds__(512) void gemm8p(
    const u16* __restrict__ A, const u16* __restrict__ Bw,
    const float* __restrict__ bias0, const float* __restrict__ bias1,
    const float* __restrict__ bias2,
    u16* __restrict__ O0, u16* __restrict__ O1, u16* __restrict__ O2,
    float* __restrict__ Of, int K) {
  __shared__ u16 sA[2][256 * 64];
  __shared__ u16 sB[2][256 * 64];

  const int tid = threadIdx.x, wave = tid >> 6, lane = tid & 63;
  const int bm = blockIdx.x * 256, bn = blockIdx.y * 256;
  const int wmh = (wave >> 2) * 64;    // A within-half row base (= wm>>1)
  const int wq  = (wave & 3) * 32;     // B within-half row base
  const int l15 = lane & 15, l4 = lane >> 4, l7 = lane & 7;

  f32x4 acc[8][4] = {};

  // staging: thread covers LDS row trow of a 64-row region, source chunk
  // pre-swizzled so LDS-linear write realizes slot = chunk^(row&7).
  const int trow = tid >> 3;                      // 0..63
  const int sch8 = ((tid & 7) ^ (trow & 7)) * 8;  // swizzled source chunk

  // A-half(qm) region s in {0,1}: LDS rows qm*128+s*64+trow <-> global row
  //   bm + s*128 + qm*64 + trow.
#define STG_A(buf, qm, s, kt)                                                 \
  async16(A + (size_t)(bm + (s)*128 + (qm)*64 + trow) * K + (kt) + sch8,      \
          &sA[buf][(((qm)*128 + (s)*64) + wave * 8) * 64])
  // B-half(qn) region s: LDS rows qn*128+s*64+trow <-> global row
  //   bn + (s*2 + (trow>>5))*64 + qn*32 + (trow&31).
#define STG_B(buf, qn, s, kt)                                                 \
  async16(Bw + (size_t)(bn + ((s)*2 + (trow >> 5)) * 64 + (qn)*32 +           \
                        (trow & 31)) * K + (kt) + sch8,                       \
          &sB[buf][(((qn)*128 + (s)*64) + wave * 8) * 64])

  bf16x8 af[4][2], bq[2][2];

#define PH_READS(buf, qm, qn)                                                 \
  _Pragma("unroll") for (int m = 0; m < 4; m++)                               \
    _Pragma("unroll") for (int kk = 0; kk < 2; kk++)                          \
      af[m][kk] = *(const bf16x8*)&sA[buf][((qm)*128 + wmh + m * 16 + l15) * 64 \
                                           + ((kk * 4 + l4) ^ l7) * 8];       \
  _Pragma("unroll") for (int n = 0; n < 2; n++)                               \
    _Pragma("unroll") for (int kk = 0; kk < 2; kk++)                          \
      bq[n][kk] = *(const bf16x8*)&sB[buf][((qn)*128 + wq + n * 16 + l15) * 64 \
                                           + ((kk * 4 + l4) ^ l7) * 8];

#define PH_MFMA(qm, qn)                                                       \
  __builtin_amdgcn_s_barrier();                                               \
  asm volatile("s_waitcnt lgkmcnt(0)" ::: "memory");                          \
  __builtin_amdgcn_s_setprio(1);                                              \
  _Pragma("unroll") for (int kk = 0; kk < 2; kk++)                            \
    _Pragma("unroll") for (int m = 0; m < 4; m++)                             \
      _Pragma("unroll") for (int n = 0; n < 2; n++)                           \
        acc[(qm)*4 + m][(qn)*2 + n] = __builtin_amdgcn_mfma_f32_16x16x32_bf16(\
            af[m][kk], bq[n][kk], acc[(qm)*4 + m][(qn)*2 + n], 0, 0, 0);      \
  __builtin_amdgcn_s_setprio(0);                                              \
  __builtin_amdgcn_s_barrier();                                               \
  asm volatile("" ::: "memory");

  // prologue: t0 {A0,B0,A1,B1}, t1 {A0,B0}; wait t0 done (4 youngest allowed)
  STG_A(0, 0, 0, 0);  STG_A(0, 0, 1, 0);
  STG_B(0, 0, 0, 0);  STG_B(0, 0, 1, 0);
  STG_A(0, 1, 0, 0);  STG_A(0, 1, 1, 0);
  STG_B(0, 1, 0, 0);  STG_B(0, 1, 1, 0);
  STG_A(1, 0, 0, 64); STG_A(1, 0, 1, 64);
  STG_B(1, 0, 0, 64); STG_B(1, 0, 1, 64);
  asm volatile("s_waitcnt vmcnt(4)" ::: "memory");
  __builtin_amdgcn_s_barrier();
  asm volatile("" ::: "memory");

  const int NT = K >> 6;      // K-tiles of 64
  const int NI = NT >> 1;     // 2 tiles per iteration
  for (int i = 0; i < NI; ++i) {
    const int kO  = (2 * i + 1) * 64;
    const int kE2 = (2 * i + 2) * 64;
    const int kO2 = (2 * i + 3) * 64;
    const bool gE2 = (2 * i + 2) < NT;
    const bool gO2 = (2 * i + 3) < NT;

    // p0: read E(A0,B0); stage O.A1 -> buf1
    PH_READS(0, 0, 0);
    STG_A(1, 1, 0, kO); STG_A(1, 1, 1, kO);
    PH_MFMA(0, 0);
    // p1: read E(A0,B1); stage O.B1 -> buf1
    PH_READS(0, 0, 1);
    STG_B(1, 1, 0, kO); STG_B(1, 1, 1, kO);
    PH_MFMA(0, 1);
    // p2: read E(A1,B0); stage E2.A0 -> buf0
    PH_READS(0, 1, 0);
    if (gE2) { STG_A(0, 0, 0, kE2); STG_A(0, 0, 1, kE2); }
    PH_MFMA(1, 0);
    // p3: read E(A1,B1); stage E2.B0; WAIT protecting p4-p7 (tile O)
    PH_READS(0, 1, 1);
    if (gE2) {
      STG_B(0, 0, 0, kE2); STG_B(0, 0, 1, kE2);
      asm volatile("s_waitcnt vmcnt(4)" ::: "memory");
    } else {
      asm volatile("s_waitcnt vmcnt(0)" ::: "memory");
    }
    PH_MFMA(1, 1);
    // p4: read O(A0,B0); stage E2.A1 -> buf0
    PH_READS(1, 0, 0);
    if (gE2) { STG_A(0, 1, 0, kE2); STG_A(0, 1, 1, kE2); }
    PH_MFMA(0, 0);
    // p5: read O(A0,B1); stage E2.B1 -> buf0
    PH_READS(1, 0, 1);
    if (gE2) { STG_B(0, 1, 0, kE2); STG_B(0, 1, 1, kE2); }
    PH_MFMA(0, 1);
    // p6: read O(A1,B0); stage O2.A0 -> buf1
    PH_READS(1, 1, 0);
    if (gO2) { STG_A(1, 0, 0, kO2); STG_A(1, 0, 1, kO2); }
    PH_MFMA(1, 0);
    // p7: read O(A1,B1); stage O2.B0; WAIT protecting next iter's p0-p3
    PH_READS(1, 1, 1);
    if (gO2) { STG_B(1, 0, 0, kO2); STG_B(1, 0, 1, kO2); }
    asm volatile("s_waitcnt vmcnt(4)" ::: "memory");
    PH_MFMA(1, 1);
  }
#undef STG_A
#undef STG_B
#undef PH_READS
#undef PH_MFMA

  // epilogue. C/D layout: col=lane&15, row=(lane>>4)*4+j (verified).
  const int wm = wmh * 2;
  const int wn = (wave & 3) * 64;
  const int r0 = l4 * 4, cc = l15;
  if constexpr (MODE == 1) {
    const int mat = blockIdx.y >> 2;                    // 0=Q 1=K 2=V
    u16* outp = (mat == 0) ? O0 : (mat == 1) ? O1 : O2;
    const float* bias = (mat == 0) ? bias0 : (mat == 1) ? bias1 : bias2;
    const int act = (mat < 2);
    const int colb = (blockIdx.y & 3) * 256;
    float bvv[4];
#pragma unroll
    for (int ni = 0; ni < 4; ni++) bvv[ni] = bias[colb + wn + ni * 16 + cc];
#pragma unroll
    for (int mi = 0; mi < 8; mi++) {
#pragma unroll
      for (int j = 0; j < 4; j++) {
        const int row = bm + wm + mi * 16 + r0 + j;
#pragma unroll
        for (int ni = 0; ni < 4; ni++) {               // ni inner: line-merge
          const int col = colb + wn + ni * 16 + cc;
          float val = acc[mi][ni][j] + bvv[ni];
          if (act) val = (val > 0.f) ? (val + 1.f) : __expf(val);  // phi
          outp[(size_t)row * 1024 + col] = f2bf(val);
        }
      }
    }
  } else {
    float bvv[4];
#pragma unroll
    for (int ni = 0; ni < 4; ni++) bvv[ni] = bias0[bn + wn + ni * 16 + cc];
#pragma unroll
    for (int mi = 0; mi < 8; mi++) {
#pragma unroll
      for (int j = 0; j < 4; j++) {
        const int row = bm + wm + mi * 16 + r0 + j;
#pragma unroll
        for (int ni = 0; ni < 4; ni++) {
          const int col = bn + wn + ni * 16 + cc;
          Of[(size_t)row * 1024 + col] = acc[mi][ni][j] + bvv[ni];
        }
      }
    }
  }
}

// ---------- kv via MFMA: kv[bh][d][m] = sum_t K[t,d]*V[t,m]; ksum via ones-B ----------
__global__ __launch_bounds__(256) void kv_mfma_kernel(
    const u16* __restrict__ Kb, const u16* __restrict__ Vb,
    float* __restrict__ kv, float* __restrict__ ksum) {
  const int bh = blockIdx.y;
  const int chunk = blockIdx.x;
  const int b = bh >> 4, h = bh & 15;
  const int tid = threadIdx.x, wave = tid >> 6, lane = tid & 63;

  __shared__ u16 sKT[64 * 64];
  __shared__ u16 sVT[64 * 64];

  f32x4 acc[4] = {};
  f32x4 accs[4] = {};

  union { u16x8v u; bf16x8 b; } uo;
#pragma unroll
  for (int e = 0; e < 8; e++) uo.u[e] = 0x3F80;
  const bf16x8 ones = uo.b;

  const int half = tid >> 7;
  const int j    = tid & 127;
  const int tg   = j >> 3;
  const int dg   = j & 7;
  const u16* src = half ? Vb : Kb;
  u16* dst = half ? sVT : sKT;
  const int colb = (4 * tg + 8 * dg) & 63;

  const size_t rowBase = (size_t)b * 4096 + (size_t)chunk * 512;
  const size_t gbase = (rowBase + 4 * tg) * 1024 + (size_t)h * 64 + dg * 8;

  u16x8v pre[2][4];
#pragma unroll
  for (int s = 0; s < 4; s++)
    pre[0][s] = *(const u16x8v*)(src + gbase + (size_t)s * 1024);

#pragma unroll
  for (int st = 0; st < 8; st++) {
    const int cb = st & 1;
    __syncthreads();
#pragma unroll
    for (int e = 0; e < 8; e++) {
      u16x4 w;
      w[0] = pre[cb][0][e]; w[1] = pre[cb][1][e];
      w[2] = pre[cb][2][e]; w[3] = pre[cb][3][e];
      *(u16x4*)&dst[(dg * 8 + e) * 64 + colb] = w;
    }
    if (st + 1 < 8) {
      const size_t nb = gbase + (size_t)(st + 1) * 64 * 1024;
#pragma unroll
      for (int s = 0; s < 4; s++)
        pre[cb ^ 1][s] = *(const u16x8v*)(src + nb + (size_t)s * 1024);
    }
    __syncthreads();

#pragma unroll
    for (int kst = 0; kst < 2; kst++) {
      const int q8 = kst * 32 + (lane >> 4) * 8;
      bf16x8 bfrag;
      {
        const int rr = wave * 16 + (lane & 15);
        const int c = (q8 + 8 * (rr >> 3)) & 63;
        bfrag = *(const bf16x8*)&sVT[rr * 64 + c];
      }
#pragma unroll
      for (int i = 0; i < 4; i++) {
        const int rr = i * 16 + (lane & 15);
        const int c = (q8 + 8 * (rr >> 3)) & 63;
        const bf16x8 afrag = *(const bf16x8*)&sKT[rr * 64 + c];
        acc[i] = __builtin_amdgcn_mfma_f32_16x16x32_bf16(afrag, bfrag, acc[i], 0, 0, 0);
        if (wave == 0)
          accs[i] = __builtin_amdgcn_mfma_f32_16x16x32_bf16(afrag, ones, accs[i], 0, 0, 0);
      }
    }
  }

  const int r0 = (lane >> 4) * 4, cc = lane & 15;
  float* kvp = kv + (size_t)bh * 4096;
#pragma unroll
  for (int i = 0; i < 4; i++)
#pragma unroll
    for (int jj = 0; jj < 4; jj++)
      atomicAdd(&kvp[(size_t)(i * 16 + r0 + jj) * 64 + wave * 16 + cc], acc[i][jj]);
  if (wave == 0 && cc == 0) {
#pragma unroll
    for (int i = 0; i < 4; i++)
#pragma unroll
      for (int jj = 0; jj < 4; jj++)
        atomicAdd(&ksum[(size_t)bh * 64 + i * 16 + r0 + jj], accs[i][jj]);
  }
}

// ---------- attn[t, h*64+m] = (Q[t,:] @ kv) * z[t] ----------
#define QST 80
__global__ __launch_bounds__(256) void attn_apply_kernel(
    const u16* __restrict__ Qb, const float* __restrict__ kv,
    const float* __restrict__ ksum, u16* __restrict__ attn) {
  const int bh = blockIdx.y;
  const int tt = blockIdx.x;
  const int b = bh >> 4, h = bh & 15;
  const int tid = threadIdx.x, wave = tid >> 6, lane = tid & 63;

  __shared__ u16 skvT[64 * QST];
  __shared__ u16 sq[64 * QST];
  __shared__ float sz[64];
  __shared__ float sks[64];

  if (tid < 64) sks[tid] = ksum[(size_t)bh * 64 + tid] + EPS;

  const float* kvp = kv + (size_t)bh * 4096;
  for (int i = tid; i < 4096; i += 256) {
    const int dd = i >> 6, mm = i & 63;
    skvT[mm * QST + dd] = f2bf(kvp[i]);
  }
  const size_t qbase = ((size_t)b * 4096 + (size_t)tt * 64) * 1024 + h * 64;
  for (int i = tid; i < 4096; i += 256) {
    const int r = i >> 6, dd = i & 63;
    sq[r * QST + dd] = Qb[qbase + (size_t)r * 1024 + dd];
  }
  __syncthreads();

  if (tid < 64) {
    float za = 0.f;
#pragma unroll
    for (int j = 0; j < 64; j++) {
      const int dd = (j + tid) & 63;
      za += bf2f(sq[tid * QST + dd]) * sks[dd];
    }
    sz[tid] = 1.f / (za + EPS);
  }
  __syncthreads();

  f32x4 acc[4] = {};
#pragma unroll
  for (int ks2 = 0; ks2 < 2; ks2++) {
    const bf16x8 a = *(const bf16x8*)&sq[(wave * 16 + (lane & 15)) * QST + ks2 * 32 + (lane >> 4) * 8];
#pragma unroll
    for (int ni = 0; ni < 4; ni++) {
      const bf16x8 bv = *(const bf16x8*)&skvT[(ni * 16 + (lane & 15)) * QST + ks2 * 32 + (lane >> 4) * 8];
      acc[ni] = __builtin_amdgcn_mfma_f32_16x16x32_bf16(a, bv, acc[ni], 0, 0, 0);
    }
  }

  const int r0 = (lane >> 4) * 4, cc = lane & 15;
#pragma unroll
  for (int ni = 0; ni < 4; ni++) {
#pragma unroll
    for (int j = 0; j < 4; j++) {
      const int r = wave * 16 + r0 + j;
      const int c = ni * 16 + cc;
      const float val = acc[ni][j] * sz[r];
      attn[qbase + (size_t)r * 1024 + c] = f2bf(val);
    }
  }
}

// ---------- launch ----------
extern "C" void kernel_launch(void* const* d_in, const int* in_sizes, int n_in,
                              void* d_out, int out_size, void* d_ws, size_t ws_size,
                              hipStream_t stream) {
  (void)in_sizes; (void)n_in; (void)out_size; (void)ws_size;
  const float* x  = (const float*)d_in[0];
  const float* Wq = (const float*)d_in[1];
  const float* bq = (const float*)d_in[2];
  const float* Wk = (const float*)d_in[3];
  const float* bk = (const float*)d_in[4];
  const float* Wv = (const float*)d_in[5];
  const float* bv = (const float*)d_in[6];
  const float* Wo = (const float*)d_in[7];
  const float* bo = (const float*)d_in[8];

  // B=4, T=4096, D=1024, H=16, DK=64; M = B*T = 16384
  char* ws = (char*)d_ws;
  u16* xb    = (u16*)ws;  ws += 33554432;              // [16384,1024] bf16
  u16* wqkvb = (u16*)ws;  ws += 6291456;               // [3072,1024] bf16 (Q|K|V)
  u16* wob   = (u16*)ws;  ws += 2097152;
  u16* Vb    = (u16*)ws;  ws += 33554432;
  u16* attn  = (u16*)ws;  ws += 33554432;
  float* kvb  = (float*)ws; ws += 1048576;             // [64][64][64] fp32
  float* ksum = (float*)ws; ws += 16384;               // [64][64] fp32

  u16* Qb = (u16*)d_out;
  u16* Kb = Qb + 16777216;

  hipMemsetAsync(kvb, 0, 1048576 + 16384, stream);

  cvt_bf16_kernel<<<8192, 256, 0, stream>>>(x, xb, 2097152);
  cvt_w_kernel<<<2048, 256, 0, stream>>>(Wq, Wk, Wv, Wo,
                                         wqkvb, wqkvb + 1048576, wqkvb + 2097152, wob);

  // fused QKV GEMM: [16384,1024] x [3072,1024]^T, N=3072
  gemm8p<1><<<dim3(64, 12), 512, 0, stream>>>(
      xb, wqkvb, bq, bk, bv, Qb, Kb, Vb, nullptr, 1024);

  kv_mfma_kernel<<<dim3(8, 64), dim3(256), 0, stream>>>(Kb, Vb, kvb, ksum);
  attn_apply_kernel<<<dim3(64, 64), dim3(256), 0, stream>>>(Qb, kvb, ksum, attn);

  // output GEMM: [16384,1024] x [1024,1024]^T -> fp32
  gemm8p<0><<<dim3(64, 4), 512, 0, stream>>>(
      attn, wob, bo, nullptr, nullptr, nullptr, nullptr, nullptr,
      (float*)d_out, 1024);
}

// Round 4
// 319.746 us; speedup vs baseline: 1.2906x; 1.0571x over previous
//
#include <hip/hip_runtime.h>
#include <cstdint>
#include <cstddef>

typedef unsigned short u16;
typedef __bf16 bf16x8 __attribute__((ext_vector_type(8)));
typedef float  f32x4  __attribute__((ext_vector_type(4)));
typedef u16    u16x8v __attribute__((ext_vector_type(8)));
typedef u16    u16x4  __attribute__((ext_vector_type(4)));

#define EPS 1e-6f

// ---------- helpers ----------
__device__ __forceinline__ u16 f2bf(float f) {
  union { float f; unsigned int u; } v; v.f = f;
  unsigned int u = v.u + 0x7FFFu + ((v.u >> 16) & 1u);   // RNE
  return (u16)(u >> 16);
}
__device__ __forceinline__ float bf2f(u16 h) {
  union { unsigned int u; float f; } v; v.u = ((unsigned int)h) << 16;
  return v.f;
}
__device__ __forceinline__ void async16(const void* g, void* l) {
  __builtin_amdgcn_global_load_lds(
      (const __attribute__((address_space(1))) void*)g,
      (__attribute__((address_space(3))) void*)l, 16, 0, 0);
}

// ---------- fp32 -> bf16 conversion ----------
__global__ __launch_bounds__(256) void cvt_bf16_kernel(
    const float* __restrict__ in, u16* __restrict__ out, int n8) {
  int i = blockIdx.x * 256 + threadIdx.x;
  if (i >= n8) return;
  const float4* p = (const float4*)in;
  float4 a = p[2 * (size_t)i], b = p[2 * (size_t)i + 1];
  u16x8v o;
  o[0] = f2bf(a.x); o[1] = f2bf(a.y); o[2] = f2bf(a.z); o[3] = f2bf(a.w);
  o[4] = f2bf(b.x); o[5] = f2bf(b.y); o[6] = f2bf(b.z); o[7] = f2bf(b.w);
  *(u16x8v*)(out + 8 * (size_t)i) = o;
}

__global__ __launch_bounds__(256) void cvt_w_kernel(
    const float* __restrict__ w0, const float* __restrict__ w1,
    const float* __restrict__ w2, const float* __restrict__ w3,
    u16* __restrict__ o0, u16* __restrict__ o1,
    u16* __restrict__ o2, u16* __restrict__ o3) {
  const int gb = blockIdx.x;
  const float* in = (gb < 512) ? w0 : (gb < 1024) ? w1 : (gb < 1536) ? w2 : w3;
  u16* out = (gb < 512) ? o0 : (gb < 1024) ? o1 : (gb < 1536) ? o2 : o3;
  const int i = (gb & 511) * 256 + threadIdx.x;
  const float4* p = (const float4*)in;
  float4 a = p[2 * (size_t)i], b = p[2 * (size_t)i + 1];
  u16x8v o;
  o[0] = f2bf(a.x); o[1] = f2bf(a.y); o[2] = f2bf(a.z); o[3] = f2bf(a.w);
  o[4] = f2bf(b.x); o[5] = f2bf(b.y); o[6] = f2bf(b.z); o[7] = f2bf(b.w);
  *(u16x8v*)(out + 8 * (size_t)i) = o;
}

// ---------- 256x256 4-phase NT GEMM, counted vmcnt, minimum LDS reads ----------
// 512 thr = 8 waves (2M x 4N), per-wave C = 128x64. BK=64. LDS = 2 bufs x 64KB.
// Per K-tile per wave: B-full kept in regs (bq[4][2], read once, 8 b128) +
// A in 2 halves (af[4][2], 8 b128 each) = 24 reads/tile = MINIMUM (R3 read 48
// -> LDS-bound; that was the R3 failure). 2 phases/tile, 32 MFMA each.
// Staging per iter (tiles E=2i buf0, O=2i+1 buf1; stage T2=2i+2, T3=2i+3):
//   p0:+T1.A1(2)  p1:+T2.B(4)+T2.A0(2)  p2:+T2.A1(2)  p3:+T3.B(4)+T3.A0(2)
// WAR: each half dies >=1 closing barrier before its slot restages (checked).
// RAW: uniform vmcnt(8) before each closing barrier retires exactly the
// feeders of the phase-after-next (issue-order enumeration; 2 phases slack).
// Prologue: 14 loads + vmcnt(6). Last iter peeled with waits (8,2,0,0).
// Chunk swizzle (0-conflict, R1-verified): slot = chunk ^ (row&7), source
// pre-swizzled, read XORed.
template <int MODE>
__global__ __launch_bounds__(512) void gemm4p(
    const u16* __restrict__ A, const u16* __restrict__ Bw,
    const float* __restrict__ bias0, const float* __restrict__ bias1,
    const float* __restrict__ bias2,
    u16* __restrict__ O0, u16* __restrict__ O1, u16* __restrict__ O2,
    float* __restrict__ Of, int K) {
  __shared__ u16 sA[2][256 * 64];
  __shared__ u16 sB[2][256 * 64];

  const int tid = threadIdx.x, wave = tid >> 6, lane = tid & 63;
  const int bm = blockIdx.x * 256, bn = blockIdx.y * 256;
  const int wmh = (wave >> 2) * 64;    // A within-half row base
  const int wq  = (wave & 3) * 32;     // B within-half row base
  const int l15 = lane & 15, l4 = lane >> 4, l7 = lane & 7;

  f32x4 acc[8][4] = {};

  const int trow = tid >> 3;                      // 0..63
  const int sch8 = ((tid & 7) ^ (trow & 7)) * 8;  // swizzled source chunk

  // A-half(qm) region s: LDS rows qm*128+s*64+trow <-> global row
  //   bm + s*128 + qm*64 + trow.
#define STG_A(buf, qm, s, kt)                                                 \
  async16(A + (size_t)(bm + (s)*128 + (qm)*64 + trow) * K + (kt) + sch8,      \
          &sA[buf][(((qm)*128 + (s)*64) + wave * 8) * 64])
  // B-half(qn) region s: LDS rows qn*128+s*64+trow <-> global row
  //   bn + (s*2 + (trow>>5))*64 + qn*32 + (trow&31).
#define STG_B(buf, qn, s, kt)                                                 \
  async16(Bw + (size_t)(bn + ((s)*2 + (trow >> 5)) * 64 + (qn)*32 +           \
                        (trow & 31)) * K + (kt) + sch8,                       \
          &sB[buf][(((qn)*128 + (s)*64) + wave * 8) * 64])

  bf16x8 af[4][2], bq[4][2];

#define RD_A(buf, qm)                                                         \
  _Pragma("unroll") for (int m = 0; m < 4; m++)                               \
    _Pragma("unroll") for (int kk = 0; kk < 2; kk++)                          \
      af[m][kk] = *(const bf16x8*)&sA[buf][((qm)*128 + wmh + m * 16 + l15) * 64 \
                                           + ((kk * 4 + l4) ^ l7) * 8];
  // bq[nf] covers output col wn + nf*16; LDS row via B-region inverse map:
  // row = (nf>>1)*128 + (wave&3)*32 + (nf&1)*16 + l15 (algebra checks out
  // against STG_B's mapping; same rows as R3's verified 2-half read).
#define RD_B(buf)                                                             \
  _Pragma("unroll") for (int nf = 0; nf < 4; nf++)                            \
    _Pragma("unroll") for (int kk = 0; kk < 2; kk++)                          \
      bq[nf][kk] = *(const bf16x8*)&sB[buf][((nf >> 1) * 128 + wq +           \
                                            (nf & 1) * 16 + l15) * 64 +       \
                                           ((kk * 4 + l4) ^ l7) * 8];

#define WAITV(n) asm volatile("s_waitcnt vmcnt(" #n ")" ::: "memory")

#define PH_EXEC(qm, NW)                                                       \
  __builtin_amdgcn_s_barrier();                                               \
  asm volatile("s_waitcnt lgkmcnt(0)" ::: "memory");                          \
  __builtin_amdgcn_sched_barrier(0);                                          \
  __builtin_amdgcn_s_setprio(1);                                              \
  _Pragma("unroll") for (int kk = 0; kk < 2; kk++)                            \
    _Pragma("unroll") for (int m = 0; m < 4; m++)                             \
      _Pragma("unroll") for (int nf = 0; nf < 4; nf++)                        \
        acc[(qm)*4 + m][nf] = __builtin_amdgcn_mfma_f32_16x16x32_bf16(        \
            af[m][kk], bq[nf][kk], acc[(qm)*4 + m][nf], 0, 0, 0);             \
  __builtin_amdgcn_s_setprio(0);                                              \
  WAITV(NW);                                                                  \
  __builtin_amdgcn_s_barrier();                                               \
  asm volatile("" ::: "memory");

#define ITER_BODY(kO, kE2, kO2, hasT2, hasT3, W0, W1, W2, W3)                 \
  /* p0: T0 (buf0) B-full + A-half0 */                                        \
  RD_B(0); RD_A(0, 0);                                                        \
  STG_A(1, 1, 0, kO); STG_A(1, 1, 1, kO);              /* T1.A1 (deferred) */ \
  PH_EXEC(0, W0);                                                             \
  /* p1: T0 A-half1 */                                                        \
  RD_A(0, 1);                                                                 \
  if (hasT2) {                                                                \
    STG_B(0, 0, 0, kE2); STG_B(0, 0, 1, kE2);                                 \
    STG_B(0, 1, 0, kE2); STG_B(0, 1, 1, kE2);          /* T2.B */             \
    STG_A(0, 0, 0, kE2); STG_A(0, 0, 1, kE2);          /* T2.A0 */            \
  }                                                                           \
  PH_EXEC(1, W1);                                                             \
  /* p2: T1 (buf1) B-full + A-half0 */                                        \
  RD_B(1); RD_A(1, 0);                                                        \
  if (hasT2) { STG_A(0, 1, 0, kE2); STG_A(0, 1, 1, kE2); } /* T2.A1 */        \
  PH_EXEC(0, W2);                                                             \
  /* p3: T1 A-half1 */                                                        \
  RD_A(1, 1);                                                                 \
  if (hasT3) {                                                                \
    STG_B(1, 0, 0, kO2); STG_B(1, 0, 1, kO2);                                 \
    STG_B(1, 1, 0, kO2); STG_B(1, 1, 1, kO2);          /* T3.B */             \
    STG_A(1, 0, 0, kO2); STG_A(1, 0, 1, kO2);          /* T3.A0 */            \
  }                                                                           \
  PH_EXEC(1, W3);

  // prologue: T0 full (B,A0,A1) + T1 (B,A0); T1.A1 deferred to iter-0 p0.
  STG_B(0, 0, 0, 0);  STG_B(0, 0, 1, 0);  STG_B(0, 1, 0, 0);  STG_B(0, 1, 1, 0);
  STG_A(0, 0, 0, 0);  STG_A(0, 0, 1, 0);
  STG_A(0, 1, 0, 0);  STG_A(0, 1, 1, 0);
  STG_B(1, 0, 0, 64); STG_B(1, 0, 1, 64); STG_B(1, 1, 0, 64); STG_B(1, 1, 1, 64);
  STG_A(1, 0, 0, 64); STG_A(1, 0, 1, 64);
  WAITV(6);                               // T0's 8 loads retired
  __builtin_amdgcn_s_barrier();
  asm volatile("" ::: "memory");

  const int NT = K >> 6;      // K-tiles of 64
  const int NI = NT >> 1;     // 2 tiles / iter (NT even)
  for (int i = 0; i < NI - 1; ++i) {
    const int kO  = (2 * i + 1) * 64;
    const int kE2 = (2 * i + 2) * 64;
    const int kO2 = (2 * i + 3) * 64;
    ITER_BODY(kO, kE2, kO2, true, true, 8, 8, 8, 8);
  }
  {  // peeled last iteration (no T2/T3)
    const int kO = (NT - 1) * 64;
    ITER_BODY(kO, 0, 0, false, false, 8, 2, 0, 0);
  }
#undef STG_A
#undef STG_B
#undef RD_A
#undef RD_B
#undef WAITV
#undef PH_EXEC
#undef ITER_BODY

  // epilogue. C/D layout: col=lane&15, row=(lane>>4)*4+j (verified).
  const int wm = wmh * 2;
  const int wn = (wave & 3) * 64;
  const int r0 = l4 * 4, cc = l15;
  if constexpr (MODE == 1) {
    const int mat = blockIdx.y >> 2;                    // 0=Q 1=K 2=V
    u16* outp = (mat == 0) ? O0 : (mat == 1) ? O1 : O2;
    const float* bias = (mat == 0) ? bias0 : (mat == 1) ? bias1 : bias2;
    const int act = (mat < 2);
    const int colb = (blockIdx.y & 3) * 256;
    float bvv[4];
#pragma unroll
    for (int ni = 0; ni < 4; ni++) bvv[ni] = bias[colb + wn + ni * 16 + cc];
#pragma unroll
    for (int mi = 0; mi < 8; mi++) {
#pragma unroll
      for (int j = 0; j < 4; j++) {
        const int row = bm + wm + mi * 16 + r0 + j;
#pragma unroll
        for (int ni = 0; ni < 4; ni++) {               // ni inner: line-merge
          const int col = colb + wn + ni * 16 + cc;
          float val = acc[mi][ni][j] + bvv[ni];
          if (act) val = (val > 0.f) ? (val + 1.f) : __expf(val);  // phi
          outp[(size_t)row * 1024 + col] = f2bf(val);
        }
      }
    }
  } else {
    float bvv[4];
#pragma unroll
    for (int ni = 0; ni < 4; ni++) bvv[ni] = bias0[bn + wn + ni * 16 + cc];
#pragma unroll
    for (int mi = 0; mi < 8; mi++) {
#pragma unroll
      for (int j = 0; j < 4; j++) {
        const int row = bm + wm + mi * 16 + r0 + j;
#pragma unroll
        for (int ni = 0; ni < 4; ni++) {
          const int col = bn + wn + ni * 16 + cc;
          Of[(size_t)row * 1024 + col] = acc[mi][ni][j] + bvv[ni];
        }
      }
    }
  }
}

// ---------- kv via MFMA: kv[bh][d][m] = sum_t K[t,d]*V[t,m]; ksum via ones-B ----------
__global__ __launch_bounds__(256) void kv_mfma_kernel(
    const u16* __restrict__ Kb, const u16* __restrict__ Vb,
    float* __restrict__ kv, float* __restrict__ ksum) {
  const int bh = blockIdx.y;
  const int chunk = blockIdx.x;
  const int b = bh >> 4, h = bh & 15;
  const int tid = threadIdx.x, wave = tid >> 6, lane = tid & 63;

  __shared__ u16 sKT[64 * 64];
  __shared__ u16 sVT[64 * 64];

  f32x4 acc[4] = {};
  f32x4 accs[4] = {};

  union { u16x8v u; bf16x8 b; } uo;
#pragma unroll
  for (int e = 0; e < 8; e++) uo.u[e] = 0x3F80;
  const bf16x8 ones = uo.b;

  const int half = tid >> 7;
  const int j    = tid & 127;
  const int tg   = j >> 3;
  const int dg   = j & 7;
  const u16* src = half ? Vb : Kb;
  u16* dst = half ? sVT : sKT;
  const int colb = (4 * tg + 8 * dg) & 63;

  const size_t rowBase = (size_t)b * 4096 + (size_t)chunk * 512;
  const size_t gbase = (rowBase + 4 * tg) * 1024 + (size_t)h * 64 + dg * 8;

  u16x8v pre[2][4];
#pragma unroll
  for (int s = 0; s < 4; s++)
    pre[0][s] = *(const u16x8v*)(src + gbase + (size_t)s * 1024);

#pragma unroll
  for (int st = 0; st < 8; st++) {
    const int cb = st & 1;
    __syncthreads();
#pragma unroll
    for (int e = 0; e < 8; e++) {
      u16x4 w;
      w[0] = pre[cb][0][e]; w[1] = pre[cb][1][e];
      w[2] = pre[cb][2][e]; w[3] = pre[cb][3][e];
      *(u16x4*)&dst[(dg * 8 + e) * 64 + colb] = w;
    }
    if (st + 1 < 8) {
      const size_t nb = gbase + (size_t)(st + 1) * 64 * 1024;
#pragma unroll
      for (int s = 0; s < 4; s++)
        pre[cb ^ 1][s] = *(const u16x8v*)(src + nb + (size_t)s * 1024);
    }
    __syncthreads();

#pragma unroll
    for (int kst = 0; kst < 2; kst++) {
      const int q8 = kst * 32 + (lane >> 4) * 8;
      bf16x8 bfrag;
      {
        const int rr = wave * 16 + (lane & 15);
        const int c = (q8 + 8 * (rr >> 3)) & 63;
        bfrag = *(const bf16x8*)&sVT[rr * 64 + c];
      }
#pragma unroll
      for (int i = 0; i < 4; i++) {
        const int rr = i * 16 + (lane & 15);
        const int c = (q8 + 8 * (rr >> 3)) & 63;
        const bf16x8 afrag = *(const bf16x8*)&sKT[rr * 64 + c];
        acc[i] = __builtin_amdgcn_mfma_f32_16x16x32_bf16(afrag, bfrag, acc[i], 0, 0, 0);
        if (wave == 0)
          accs[i] = __builtin_amdgcn_mfma_f32_16x16x32_bf16(afrag, ones, accs[i], 0, 0, 0);
      }
    }
  }

  const int r0 = (lane >> 4) * 4, cc = lane & 15;
  float* kvp = kv + (size_t)bh * 4096;
#pragma unroll
  for (int i = 0; i < 4; i++)
#pragma unroll
    for (int jj = 0; jj < 4; jj++)
      atomicAdd(&kvp[(size_t)(i * 16 + r0 + jj) * 64 + wave * 16 + cc], acc[i][jj]);
  if (wave == 0 && cc == 0) {
#pragma unroll
    for (int i = 0; i < 4; i++)
#pragma unroll
      for (int jj = 0; jj < 4; jj++)
        atomicAdd(&ksum[(size_t)bh * 64 + i * 16 + r0 + jj], accs[i][jj]);
  }
}

// ---------- attn[t, h*64+m] = (Q[t,:] @ kv) * z[t] ----------
#define QST 80
__global__ __launch_bounds__(256) void attn_apply_kernel(
    const u16* __restrict__ Qb, const float* __restrict__ kv,
    const float* __restrict__ ksum, u16* __restrict__ attn) {
  const int bh = blockIdx.y;
  const int tt = blockIdx.x;
  const int b = bh >> 4, h = bh & 15;
  const int tid = threadIdx.x, wave = tid >> 6, lane = tid & 63;

  __shared__ u16 skvT[64 * QST];
  __shared__ u16 sq[64 * QST];
  __shared__ float sz[64];
  __shared__ float sks[64];

  if (tid < 64) sks[tid] = ksum[(size_t)bh * 64 + tid] + EPS;

  const float* kvp = kv + (size_t)bh * 4096;
  for (int i = tid; i < 4096; i += 256) {
    const int dd = i >> 6, mm = i & 63;
    skvT[mm * QST + dd] = f2bf(kvp[i]);
  }
  const size_t qbase = ((size_t)b * 4096 + (size_t)tt * 64) * 1024 + h * 64;
  for (int i = tid; i < 4096; i += 256) {
    const int r = i >> 6, dd = i & 63;
    sq[r * QST + dd] = Qb[qbase + (size_t)r * 1024 + dd];
  }
  __syncthreads();

  if (tid < 64) {
    float za = 0.f;
#pragma unroll
    for (int j = 0; j < 64; j++) {
      const int dd = (j + tid) & 63;
      za += bf2f(sq[tid * QST + dd]) * sks[dd];
    }
    sz[tid] = 1.f / (za + EPS);
  }
  __syncthreads();

  f32x4 acc[4] = {};
#pragma unroll
  for (int ks2 = 0; ks2 < 2; ks2++) {
    const bf16x8 a = *(const bf16x8*)&sq[(wave * 16 + (lane & 15)) * QST + ks2 * 32 + (lane >> 4) * 8];
#pragma unroll
    for (int ni = 0; ni < 4; ni++) {
      const bf16x8 bv = *(const bf16x8*)&skvT[(ni * 16 + (lane & 15)) * QST + ks2 * 32 + (lane >> 4) * 8];
      acc[ni] = __builtin_amdgcn_mfma_f32_16x16x32_bf16(a, bv, acc[ni], 0, 0, 0);
    }
  }

  const int r0 = (lane >> 4) * 4, cc = lane & 15;
#pragma unroll
  for (int ni = 0; ni < 4; ni++) {
#pragma unroll
    for (int j = 0; j < 4; j++) {
      const int r = wave * 16 + r0 + j;
      const int c = ni * 16 + cc;
      const float val = acc[ni][j] * sz[r];
      attn[qbase + (size_t)r * 1024 + c] = f2bf(val);
    }
  }
}

// ---------- launch ----------
extern "C" void kernel_launch(void* const* d_in, const int* in_sizes, int n_in,
                              void* d_out, int out_size, void* d_ws, size_t ws_size,
                              hipStream_t stream) {
  (void)in_sizes; (void)n_in; (void)out_size; (void)ws_size;
  const float* x  = (const float*)d_in[0];
  const float* Wq = (const float*)d_in[1];
  const float* bq = (const float*)d_in[2];
  const float* Wk = (const float*)d_in[3];
  const float* bk = (const float*)d_in[4];
  const float* Wv = (const float*)d_in[5];
  const float* bv = (const float*)d_in[6];
  const float* Wo = (const float*)d_in[7];
  const float* bo = (const float*)d_in[8];

  // B=4, T=4096, D=1024, H=16, DK=64; M = B*T = 16384
  char* ws = (char*)d_ws;
  u16* xb    = (u16*)ws;  ws += 33554432;              // [16384,1024] bf16
  u16* wqkvb = (u16*)ws;  ws += 6291456;               // [3072,1024] bf16 (Q|K|V)
  u16* wob   = (u16*)ws;  ws += 2097152;
  u16* Vb    = (u16*)ws;  ws += 33554432;
  u16* attn  = (u16*)ws;  ws += 33554432;
  float* kvb  = (float*)ws; ws += 1048576;             // [64][64][64] fp32
  float* ksum = (float*)ws; ws += 16384;               // [64][64] fp32

  u16* Qb = (u16*)d_out;
  u16* Kb = Qb + 16777216;

  hipMemsetAsync(kvb, 0, 1048576 + 16384, stream);

  cvt_bf16_kernel<<<8192, 256, 0, stream>>>(x, xb, 2097152);
  cvt_w_kernel<<<2048, 256, 0, stream>>>(Wq, Wk, Wv, Wo,
                                         wqkvb, wqkvb + 1048576, wqkvb + 2097152, wob);

  // fused QKV GEMM: [16384,1024] x [3072,1024]^T, N=3072
  gemm4p<1><<<dim3(64, 12), 512, 0, stream>>>(
      xb, wqkvb, bq, bk, bv, Qb, Kb, Vb, nullptr, 1024);

  kv_mfma_kernel<<<dim3(8, 64), dim3(256), 0, stream>>>(Kb, Vb, kvb, ksum);
  attn_apply_kernel<<<dim3(64, 64), dim3(256), 0, stream>>>(Qb, kvb, ksum, attn);

  // output GEMM: [16384,1024] x [1024,1024]^T -> fp32
  gemm4p<0><<<dim3(64, 4), 512, 0, stream>>>(
      attn, wob, bo, nullptr, nullptr, nullptr, nullptr, nullptr,
      (float*)d_out, 1024);
}